// Round 2
// 219.506 us; speedup vs baseline: 1.0127x; 1.0127x over previous
//
#include <hip/hip_runtime.h>
#include <stdint.h>
#include <stddef.h>

#define Bn 32
#define Cc 512
#define Hh 40
#define Ww 40
#define Npix 1600
#define NCx 20
#define NCELL (Bn*Npix)      // 51200
#define CONF 0.3f
#define NMS_T 0.5f
#define NOUT 25
#define WSTRIDE 32           // padded packed-weight row stride (floats), rows 128B-aligned

// k1 geometry: 128 cells/block (2 cells/lane via float2), 4 waves split C,
// grid = NCELL/128 = 400 blocks. Per-cell FMA chain order identical to the
// proven R0/R3 arithmetic (bit-identical outputs).
#define CB2 128
#define NBLK (NCELL/CB2)     // 400
#define NWAVE 4
#define CR (Cc/NWAVE)        // 128 channels per wave

// workspace layout (float offsets)
#define WS_WPK    0
#define WS_BOXES  (WS_WPK + (size_t)Cc*WSTRIDE)
#define WS_SCORES (WS_BOXES + (size_t)NCELL*4)
#define WS_LABELS (WS_SCORES + (size_t)NCELL)

__device__ __forceinline__ float sigmoidf_(float x) {
    return 1.0f / (1.0f + expf(-x));
}

// ---------------- Kernel 0: pack weights into [c][WSTRIDE] rows ----------------
__global__ __launch_bounds__(64) void k0_pack(
    const float* __restrict__ w_obj, const float* __restrict__ w_cls,
    const float* __restrict__ w_reg, float* __restrict__ Wpk)
{
    int c = blockIdx.x * 64 + threadIdx.x;
    if (c < Cc) {
        float* row = Wpk + (size_t)c * WSTRIDE;
        row[0] = w_obj[c];
        #pragma unroll
        for (int o = 0; o < NCx; ++o) row[1 + o] = w_cls[o * Cc + c];
        #pragma unroll
        for (int o = 0; o < 4; ++o)   row[21 + o] = w_reg[o * Cc + c];
        row[25] = 0.f; row[26] = 0.f; row[27] = 0.f;
        row[28] = 0.f; row[29] = 0.f; row[30] = 0.f; row[31] = 0.f;
    }
}

// ---------------- Kernel 1: fused GEMM + reduce + decode + out-init ----------------
// block = 256 thr (4 waves). Wave w handles channels [w*128, w*128+128) for the
// block's 128 cells, TWO cells per lane (float2 loads: 8B/lane, 512B/wave,
// coalesced). Total VMEM instrs halved vs 1-cell/lane at identical bytes;
// 50 independent FMA chains per lane for ILP. Per-cell FMA chain and the
// sequential 4-chunk combine are bit-identical to the proven arithmetic.
// LDS reduce 64000B (<64KB static limit); grid 400 is the occupancy limiter.
__global__ __launch_bounds__(256) void k1_fused(
    const float* __restrict__ feat, const float* __restrict__ Wpk,
    const float* __restrict__ b_obj, const float* __restrict__ b_cls,
    const float* __restrict__ b_reg,
    float* __restrict__ out, float* __restrict__ ws_boxes,
    float* __restrict__ ws_scores, int* __restrict__ ws_labels)
{
    __shared__ float red[NOUT][CB2][5];   // [o][cell][wave] = 64000 B

    const int tid = threadIdx.x;
    const int w   = __builtin_amdgcn_readfirstlane(tid >> 6);  // uniform -> scalar path
    const int l   = tid & 63;
    const int g0  = blockIdx.x * CB2;      // first flattened cell of block

    // lane's cell pair: gp, gp+1 (always same image: Npix even, gp even)
    const int gp = g0 + 2 * l;
    const int bb = gp / Npix;
    const int nn = gp - bb * Npix;

    float acc0[NOUT], acc1[NOUT];
    #pragma unroll
    for (int o = 0; o < NOUT; ++o) { acc0[o] = 0.f; acc1[o] = 0.f; }

    const int cw0 = w * CR;
    {
        const float* fp  = feat + (size_t)bb * (Cc * Npix) + (size_t)cw0 * Npix + nn;
        const float* wr0 = Wpk + (size_t)cw0 * WSTRIDE;
        #pragma unroll 8
        for (int cc = 0; cc < CR; ++cc) {
            float2 x = *(const float2*)(fp + (size_t)cc * Npix);
            const float4* wq = (const float4*)(wr0 + cc * WSTRIDE);  // uniform -> s_load
            #pragma unroll
            for (int q = 0; q < 6; ++q) {
                float4 wv = wq[q];
                const int ob = q * 4;
                acc0[ob+0] = fmaf(x.x, wv.x, acc0[ob+0]);
                acc0[ob+1] = fmaf(x.x, wv.y, acc0[ob+1]);
                acc0[ob+2] = fmaf(x.x, wv.z, acc0[ob+2]);
                acc0[ob+3] = fmaf(x.x, wv.w, acc0[ob+3]);
                acc1[ob+0] = fmaf(x.y, wv.x, acc1[ob+0]);
                acc1[ob+1] = fmaf(x.y, wv.y, acc1[ob+1]);
                acc1[ob+2] = fmaf(x.y, wv.z, acc1[ob+2]);
                acc1[ob+3] = fmaf(x.y, wv.w, acc1[ob+3]);
            }
            float4 wv6 = wq[6];                    // only .x is real (o=24)
            acc0[24] = fmaf(x.x, wv6.x, acc0[24]);
            acc1[24] = fmaf(x.y, wv6.x, acc1[24]);
        }
        #pragma unroll
        for (int o = 0; o < NOUT; ++o) {
            red[o][2*l  ][w] = acc0[o];
            red[o][2*l+1][w] = acc1[o];
        }
    }
    __syncthreads();

    if (tid < CB2) {
        float v[NOUT];
        // SEQUENTIAL combine (((w0+w1)+w2)+w3) — proven ordering.
        #pragma unroll
        for (int o = 0; o < NOUT; ++o) v[o] = red[o][tid][0];
        #pragma unroll
        for (int ch = 1; ch < NWAVE; ++ch) {
            #pragma unroll
            for (int o = 0; o < NOUT; ++o) v[o] += red[o][tid][ch];
        }

        float obj = v[0] + b_obj[0];
        float m = -1e30f; int label = 0;
        #pragma unroll
        for (int o = 0; o < NCx; ++o) {
            float cv = v[1 + o] + b_cls[o];
            if (cv > m) { m = cv; label = o; }   // strict > == first-max (argmax)
        }
        float r0 = v[21] + b_reg[0], r1 = v[22] + b_reg[1];
        float r2 = v[23] + b_reg[2], r3 = v[24] + b_reg[3];

        int g = g0 + tid;
        int b = g / Npix;
        int n = g - b * Npix;
        int gy = n / Ww, gx = n % Ww;
        float cx = (sigmoidf_(r0) + (float)gx) * 32.0f;
        float cy = (sigmoidf_(r1) + (float)gy) * 32.0f;
        float bw = expf(r2) * 32.0f;
        float bh = expf(r3) * 32.0f;
        float x1 = cx - bw * 0.5f, y1 = cy - bh * 0.5f;
        float x2 = cx + bw * 0.5f, y2 = cy + bh * 0.5f;
        float score = sqrtf(sigmoidf_(obj) * sigmoidf_(m));

        ((float4*)ws_boxes)[g] = make_float4(x1, y1, x2, y2);
        ws_scores[g] = score;
        ws_labels[g] = label;

        float* orow = out + (size_t)g * 5;
        orow[0] = 0.f; orow[1] = 0.f; orow[2] = 0.f; orow[3] = 0.f; orow[4] = 0.f;
        out[(size_t)NCELL * 5 + g] = (float)label;
        out[(size_t)NCELL * 6 + g] = 0.f;
    }
}

// ---------------- Kernel 3: per-(image,class) greedy NMS (proven, unchanged) ----------------
#define KSUP 320
#define WUMAX ((KSUP + 31) / 32)   // 10

__global__ __launch_bounds__(256) void k3_nms(
    const float4* __restrict__ ws_boxes, const float* __restrict__ ws_scores,
    const int* __restrict__ ws_labels, float* __restrict__ out)
{
    __shared__ unsigned int cnt;
    __shared__ unsigned long long keys[2048];
    __shared__ float bx1[Npix], by1[Npix], bx2[Npix], by2[Npix], bar[Npix];
    __shared__ unsigned int sup[KSUP * WUMAX];   // reused as keep-flags later
    __shared__ unsigned int keepbits[WUMAX];

    const int tid = threadIdx.x;
    const int b   = blockIdx.x / NCx;
    const int cls = blockIdx.x % NCx;
    const int gbase = b * Npix;

    if (tid == 0) cnt = 0;
    __syncthreads();

    for (int n = tid; n < Npix; n += 256) {
        float s = ws_scores[gbase + n];
        if (s > CONF && ws_labels[gbase + n] == cls) {
            unsigned int pos = atomicAdd(&cnt, 1u);
            unsigned int sb = __float_as_uint(s);
            keys[pos] = ((unsigned long long)(~sb) << 32) | (unsigned int)n;
        }
    }
    __syncthreads();
    const int k = (int)cnt;
    if (k == 0) return;

    int M = 2; while (M < k) M <<= 1;
    for (int s = tid; s < M; s += 256) if (s >= k) keys[s] = ~0ull;
    __syncthreads();

    for (int sz = 2; sz <= M; sz <<= 1) {
        for (int st = sz >> 1; st > 0; st >>= 1) {
            for (int t = tid; t < M; t += 256) {
                int p = t ^ st;
                if (p > t) {
                    unsigned long long a = keys[t], c = keys[p];
                    bool up = ((t & sz) == 0);
                    if (up ? (a > c) : (a < c)) { keys[t] = c; keys[p] = a; }
                }
            }
            __syncthreads();
        }
    }

    for (int s = tid; s < k; s += 256) {
        int n = (int)(unsigned int)keys[s];
        float4 bx = ws_boxes[gbase + n];
        bx1[s] = bx.x; by1[s] = bx.y; bx2[s] = bx.z; by2[s] = bx.w;
        bar[s] = (bx.z - bx.x) * (bx.w - bx.y);
    }
    __syncthreads();

    if (k <= KSUP) {
        const int wu = (k + 31) >> 5;
        for (int t = tid; t < k * wu; t += 256) {
            int i = t / wu, w = t - (t / wu) * wu;
            unsigned int bits = 0;
            int j0 = w << 5;
            float xi1 = bx1[i], yi1 = by1[i], xi2 = bx2[i], yi2 = by2[i], ai = bar[i];
            for (int jj = 0; jj < 32; ++jj) {
                int j = j0 + jj;
                if (j > i && j < k) {
                    float xx1 = fmaxf(xi1, bx1[j]);
                    float yy1 = fmaxf(yi1, by1[j]);
                    float xx2 = fminf(xi2, bx2[j]);
                    float yy2 = fminf(yi2, by2[j]);
                    float inter = fmaxf(xx2 - xx1, 0.f) * fmaxf(yy2 - yy1, 0.f);
                    float uni = ai + bar[j] - inter;
                    if (inter / uni > NMS_T) bits |= (1u << jj);
                }
            }
            sup[i * wu + w] = bits;
        }
        if (tid < wu) {
            int rem = k - (tid << 5);
            keepbits[tid] = (rem >= 32) ? 0xFFFFFFFFu : ((1u << rem) - 1u);
        }
        __syncthreads();

        if (tid < 64) {
            for (int i = 0; i < k; ++i) {
                unsigned int cur = keepbits[i >> 5];
                if ((cur >> (i & 31)) & 1u) {
                    if (tid < wu) keepbits[tid] &= ~sup[i * wu + tid];
                }
            }
            unsigned int* keepF = sup;
            for (int s2 = tid; s2 < k; s2 += 64)
                keepF[s2] = (keepbits[s2 >> 5] >> (s2 & 31)) & 1u;
        }
        __syncthreads();
    } else {
        unsigned int* keepF = sup;
        for (int s = tid; s < k; s += 256) keepF[s] = 1u;
        __syncthreads();
        for (int i = 0; i < k; ++i) {
            __syncthreads();
            if (keepF[i]) {
                float xi1 = bx1[i], yi1 = by1[i], xi2 = bx2[i], yi2 = by2[i], ai = bar[i];
                for (int j = i + 1 + tid; j < k; j += 256) {
                    float xx1 = fmaxf(xi1, bx1[j]);
                    float yy1 = fmaxf(yi1, by1[j]);
                    float xx2 = fminf(xi2, bx2[j]);
                    float yy2 = fminf(yi2, by2[j]);
                    float inter = fmaxf(xx2 - xx1, 0.f) * fmaxf(yy2 - yy1, 0.f);
                    float uni = ai + bar[j] - inter;
                    if (inter / uni > NMS_T) keepF[j] = 0u;
                }
            }
        }
        __syncthreads();
    }

    unsigned int* keepF = sup;
    for (int s = tid; s < k; s += 256) {
        if (keepF[s]) {
            int n = (int)(unsigned int)keys[s];
            unsigned int sb = ~(unsigned int)(keys[s] >> 32);
            float sc = __uint_as_float(sb);
            float* orow = out + (size_t)(gbase + n) * 5;
            orow[0] = bx1[s]; orow[1] = by1[s];
            orow[2] = bx2[s]; orow[3] = by2[s];
            orow[4] = sc;
            out[(size_t)NCELL * 6 + gbase + n] = 1.0f;
        }
    }
}

extern "C" void kernel_launch(void* const* d_in, const int* in_sizes, int n_in,
                              void* d_out, int out_size, void* d_ws, size_t ws_size,
                              hipStream_t stream) {
    const float* feat  = (const float*)d_in[0];
    const float* w_obj = (const float*)d_in[1];
    const float* b_obj = (const float*)d_in[2];
    const float* w_cls = (const float*)d_in[3];
    const float* b_cls = (const float*)d_in[4];
    const float* w_reg = (const float*)d_in[5];
    const float* b_reg = (const float*)d_in[6];
    float* out = (float*)d_out;
    float* ws  = (float*)d_ws;

    float* Wpk    = ws + WS_WPK;
    float* boxes  = ws + WS_BOXES;
    float* scores = ws + WS_SCORES;
    int*   labels = (int*)(ws + WS_LABELS);

    k0_pack<<<(Cc + 63) / 64, 64, 0, stream>>>(w_obj, w_cls, w_reg, Wpk);
    k1_fused<<<NBLK, 256, 0, stream>>>(feat, Wpk, b_obj, b_cls, b_reg,
                                       out, boxes, scores, labels);
    k3_nms<<<Bn * NCx, 256, 0, stream>>>((const float4*)boxes, scores, labels, out);
}

// Round 3
// 211.926 us; speedup vs baseline: 1.0490x; 1.0358x over previous
//
#include <hip/hip_runtime.h>
#include <stdint.h>
#include <stddef.h>

#define Bn 32
#define Cc 512
#define Hh 40
#define Ww 40
#define Npix 1600
#define NCx 20
#define NCELL (Bn*Npix)      // 51200
#define CONF 0.3f
#define NMS_T 0.5f
#define NOUT 25
#define WSTRIDE 32           // padded packed-weight row stride (floats), rows 128B-aligned

// k1 geometry: 128 cells/block (2 cells/lane via float2), 4 waves split C,
// grid = NCELL/128 = 400 blocks. Per-cell FMA chain order identical to the
// proven R0/R3 arithmetic (bit-identical outputs).
#define CB2 128
#define NBLK (NCELL/CB2)     // 400
#define NWAVE 4
#define CR (Cc/NWAVE)        // 128 channels per wave

// workspace layout (float offsets)
#define WS_WPK    0
#define WS_BOXES  (WS_WPK + (size_t)Cc*WSTRIDE)
#define WS_SCORES (WS_BOXES + (size_t)NCELL*4)
#define WS_LABELS (WS_SCORES + (size_t)NCELL)

__device__ __forceinline__ float sigmoidf_(float x) {
    return 1.0f / (1.0f + expf(-x));
}

// ---------------- Kernel 0: pack weights into [c][WSTRIDE] rows ----------------
__global__ __launch_bounds__(64) void k0_pack(
    const float* __restrict__ w_obj, const float* __restrict__ w_cls,
    const float* __restrict__ w_reg, float* __restrict__ Wpk)
{
    int c = blockIdx.x * 64 + threadIdx.x;
    if (c < Cc) {
        float* row = Wpk + (size_t)c * WSTRIDE;
        row[0] = w_obj[c];
        #pragma unroll
        for (int o = 0; o < NCx; ++o) row[1 + o] = w_cls[o * Cc + c];
        #pragma unroll
        for (int o = 0; o < 4; ++o)   row[21 + o] = w_reg[o * Cc + c];
        row[25] = 0.f; row[26] = 0.f; row[27] = 0.f;
        row[28] = 0.f; row[29] = 0.f; row[30] = 0.f; row[31] = 0.f;
    }
}

// ---------------- Kernel 1: fused GEMM + reduce + decode + out-init ----------------
// block = 256 thr (4 waves). Wave w handles channels [w*128, w*128+128) for the
// block's 128 cells, TWO cells per lane (float2 loads: 8B/lane, 512B/wave,
// coalesced). Per-cell FMA chain and the sequential 4-chunk combine are
// bit-identical to the proven arithmetic. Near HBM floor (~20us) per R2.
__global__ __launch_bounds__(256) void k1_fused(
    const float* __restrict__ feat, const float* __restrict__ Wpk,
    const float* __restrict__ b_obj, const float* __restrict__ b_cls,
    const float* __restrict__ b_reg,
    float* __restrict__ out, float* __restrict__ ws_boxes,
    float* __restrict__ ws_scores, int* __restrict__ ws_labels)
{
    __shared__ float red[NOUT][CB2][5];   // [o][cell][wave] = 64000 B

    const int tid = threadIdx.x;
    const int w   = __builtin_amdgcn_readfirstlane(tid >> 6);  // uniform -> scalar path
    const int l   = tid & 63;
    const int g0  = blockIdx.x * CB2;      // first flattened cell of block

    // lane's cell pair: gp, gp+1 (always same image: Npix even, gp even)
    const int gp = g0 + 2 * l;
    const int bb = gp / Npix;
    const int nn = gp - bb * Npix;

    float acc0[NOUT], acc1[NOUT];
    #pragma unroll
    for (int o = 0; o < NOUT; ++o) { acc0[o] = 0.f; acc1[o] = 0.f; }

    const int cw0 = w * CR;
    {
        const float* fp  = feat + (size_t)bb * (Cc * Npix) + (size_t)cw0 * Npix + nn;
        const float* wr0 = Wpk + (size_t)cw0 * WSTRIDE;
        #pragma unroll 8
        for (int cc = 0; cc < CR; ++cc) {
            float2 x = *(const float2*)(fp + (size_t)cc * Npix);
            const float4* wq = (const float4*)(wr0 + cc * WSTRIDE);  // uniform -> s_load
            #pragma unroll
            for (int q = 0; q < 6; ++q) {
                float4 wv = wq[q];
                const int ob = q * 4;
                acc0[ob+0] = fmaf(x.x, wv.x, acc0[ob+0]);
                acc0[ob+1] = fmaf(x.x, wv.y, acc0[ob+1]);
                acc0[ob+2] = fmaf(x.x, wv.z, acc0[ob+2]);
                acc0[ob+3] = fmaf(x.x, wv.w, acc0[ob+3]);
                acc1[ob+0] = fmaf(x.y, wv.x, acc1[ob+0]);
                acc1[ob+1] = fmaf(x.y, wv.y, acc1[ob+1]);
                acc1[ob+2] = fmaf(x.y, wv.z, acc1[ob+2]);
                acc1[ob+3] = fmaf(x.y, wv.w, acc1[ob+3]);
            }
            float4 wv6 = wq[6];                    // only .x is real (o=24)
            acc0[24] = fmaf(x.x, wv6.x, acc0[24]);
            acc1[24] = fmaf(x.y, wv6.x, acc1[24]);
        }
        #pragma unroll
        for (int o = 0; o < NOUT; ++o) {
            red[o][2*l  ][w] = acc0[o];
            red[o][2*l+1][w] = acc1[o];
        }
    }
    __syncthreads();

    if (tid < CB2) {
        float v[NOUT];
        // SEQUENTIAL combine (((w0+w1)+w2)+w3) — proven ordering.
        #pragma unroll
        for (int o = 0; o < NOUT; ++o) v[o] = red[o][tid][0];
        #pragma unroll
        for (int ch = 1; ch < NWAVE; ++ch) {
            #pragma unroll
            for (int o = 0; o < NOUT; ++o) v[o] += red[o][tid][ch];
        }

        float obj = v[0] + b_obj[0];
        float m = -1e30f; int label = 0;
        #pragma unroll
        for (int o = 0; o < NCx; ++o) {
            float cv = v[1 + o] + b_cls[o];
            if (cv > m) { m = cv; label = o; }   // strict > == first-max (argmax)
        }
        float r0 = v[21] + b_reg[0], r1 = v[22] + b_reg[1];
        float r2 = v[23] + b_reg[2], r3 = v[24] + b_reg[3];

        int g = g0 + tid;
        int b = g / Npix;
        int n = g - b * Npix;
        int gy = n / Ww, gx = n % Ww;
        float cx = (sigmoidf_(r0) + (float)gx) * 32.0f;
        float cy = (sigmoidf_(r1) + (float)gy) * 32.0f;
        float bw = expf(r2) * 32.0f;
        float bh = expf(r3) * 32.0f;
        float x1 = cx - bw * 0.5f, y1 = cy - bh * 0.5f;
        float x2 = cx + bw * 0.5f, y2 = cy + bh * 0.5f;
        float score = sqrtf(sigmoidf_(obj) * sigmoidf_(m));

        ((float4*)ws_boxes)[g] = make_float4(x1, y1, x2, y2);
        ws_scores[g] = score;
        ws_labels[g] = label;

        float* orow = out + (size_t)g * 5;
        orow[0] = 0.f; orow[1] = 0.f; orow[2] = 0.f; orow[3] = 0.f; orow[4] = 0.f;
        out[(size_t)NCELL * 5 + g] = (float)label;
        out[(size_t)NCELL * 6 + g] = 0.f;
    }
}

// ---------------- Kernel 3: per-(image,class) greedy NMS ----------------
// R3 change: for k <= 512 (typical k~80 on this data), sort by RANK instead
// of bitonic: rank[s] = #{j : keys[j] < keys[s]} (keys unique -> total order),
// scatter to keys2, copy back. 2 barriers instead of ~28. Identical sorted
// array -> bit-identical output. Bitonic retained as the k>512 fallback.
#define KSUP 320
#define WUMAX ((KSUP + 31) / 32)   // 10
#define KRANK 512

__global__ __launch_bounds__(256) void k3_nms(
    const float4* __restrict__ ws_boxes, const float* __restrict__ ws_scores,
    const int* __restrict__ ws_labels, float* __restrict__ out)
{
    __shared__ unsigned int cnt;
    __shared__ unsigned long long keys[2048];
    __shared__ unsigned long long keys2[KRANK];
    __shared__ float bx1[Npix], by1[Npix], bx2[Npix], by2[Npix], bar[Npix];
    __shared__ unsigned int sup[KSUP * WUMAX];   // reused as keep-flags later
    __shared__ unsigned int keepbits[WUMAX];

    const int tid = threadIdx.x;
    const int b   = blockIdx.x / NCx;
    const int cls = blockIdx.x % NCx;
    const int gbase = b * Npix;

    if (tid == 0) cnt = 0;
    __syncthreads();

    for (int n = tid; n < Npix; n += 256) {
        float s = ws_scores[gbase + n];
        if (s > CONF && ws_labels[gbase + n] == cls) {
            unsigned int pos = atomicAdd(&cnt, 1u);
            unsigned int sb = __float_as_uint(s);
            keys[pos] = ((unsigned long long)(~sb) << 32) | (unsigned int)n;
        }
    }
    __syncthreads();
    const int k = (int)cnt;
    if (k == 0) return;

    if (k <= KRANK) {
        // rank-scatter sort: keys are unique (n in low bits), so ranks are a
        // permutation. Inner j-loop is wave-uniform -> LDS broadcast reads.
        for (int s = tid; s < k; s += 256) {
            unsigned long long ks = keys[s];
            int r = 0;
            for (int j = 0; j < k; ++j) r += (keys[j] < ks) ? 1 : 0;
            keys2[r] = ks;
        }
        __syncthreads();
        for (int s = tid; s < k; s += 256) keys[s] = keys2[s];
        __syncthreads();
    } else {
        int M = 2; while (M < k) M <<= 1;
        for (int s = tid; s < M; s += 256) if (s >= k) keys[s] = ~0ull;
        __syncthreads();

        for (int sz = 2; sz <= M; sz <<= 1) {
            for (int st = sz >> 1; st > 0; st >>= 1) {
                for (int t = tid; t < M; t += 256) {
                    int p = t ^ st;
                    if (p > t) {
                        unsigned long long a = keys[t], c = keys[p];
                        bool up = ((t & sz) == 0);
                        if (up ? (a > c) : (a < c)) { keys[t] = c; keys[p] = a; }
                    }
                }
                __syncthreads();
            }
        }
    }

    for (int s = tid; s < k; s += 256) {
        int n = (int)(unsigned int)keys[s];
        float4 bx = ws_boxes[gbase + n];
        bx1[s] = bx.x; by1[s] = bx.y; bx2[s] = bx.z; by2[s] = bx.w;
        bar[s] = (bx.z - bx.x) * (bx.w - bx.y);
    }
    __syncthreads();

    if (k <= KSUP) {
        const int wu = (k + 31) >> 5;
        for (int t = tid; t < k * wu; t += 256) {
            int i = t / wu, w = t - (t / wu) * wu;
            unsigned int bits = 0;
            int j0 = w << 5;
            float xi1 = bx1[i], yi1 = by1[i], xi2 = bx2[i], yi2 = by2[i], ai = bar[i];
            for (int jj = 0; jj < 32; ++jj) {
                int j = j0 + jj;
                if (j > i && j < k) {
                    float xx1 = fmaxf(xi1, bx1[j]);
                    float yy1 = fmaxf(yi1, by1[j]);
                    float xx2 = fminf(xi2, bx2[j]);
                    float yy2 = fminf(yi2, by2[j]);
                    float inter = fmaxf(xx2 - xx1, 0.f) * fmaxf(yy2 - yy1, 0.f);
                    float uni = ai + bar[j] - inter;
                    if (inter / uni > NMS_T) bits |= (1u << jj);
                }
            }
            sup[i * wu + w] = bits;
        }
        if (tid < wu) {
            int rem = k - (tid << 5);
            keepbits[tid] = (rem >= 32) ? 0xFFFFFFFFu : ((1u << rem) - 1u);
        }
        __syncthreads();

        if (tid < 64) {
            for (int i = 0; i < k; ++i) {
                unsigned int cur = keepbits[i >> 5];
                if ((cur >> (i & 31)) & 1u) {
                    if (tid < wu) keepbits[tid] &= ~sup[i * wu + tid];
                }
            }
            unsigned int* keepF = sup;
            for (int s2 = tid; s2 < k; s2 += 64)
                keepF[s2] = (keepbits[s2 >> 5] >> (s2 & 31)) & 1u;
        }
        __syncthreads();
    } else {
        unsigned int* keepF = sup;
        for (int s = tid; s < k; s += 256) keepF[s] = 1u;
        __syncthreads();
        for (int i = 0; i < k; ++i) {
            __syncthreads();
            if (keepF[i]) {
                float xi1 = bx1[i], yi1 = by1[i], xi2 = bx2[i], yi2 = by2[i], ai = bar[i];
                for (int j = i + 1 + tid; j < k; j += 256) {
                    float xx1 = fmaxf(xi1, bx1[j]);
                    float yy1 = fmaxf(yi1, by1[j]);
                    float xx2 = fminf(xi2, bx2[j]);
                    float yy2 = fminf(yi2, by2[j]);
                    float inter = fmaxf(xx2 - xx1, 0.f) * fmaxf(yy2 - yy1, 0.f);
                    float uni = ai + bar[j] - inter;
                    if (inter / uni > NMS_T) keepF[j] = 0u;
                }
            }
        }
        __syncthreads();
    }

    unsigned int* keepF = sup;
    for (int s = tid; s < k; s += 256) {
        if (keepF[s]) {
            int n = (int)(unsigned int)keys[s];
            unsigned int sb = ~(unsigned int)(keys[s] >> 32);
            float sc = __uint_as_float(sb);
            float* orow = out + (size_t)(gbase + n) * 5;
            orow[0] = bx1[s]; orow[1] = by1[s];
            orow[2] = bx2[s]; orow[3] = by2[s];
            orow[4] = sc;
            out[(size_t)NCELL * 6 + gbase + n] = 1.0f;
        }
    }
}

extern "C" void kernel_launch(void* const* d_in, const int* in_sizes, int n_in,
                              void* d_out, int out_size, void* d_ws, size_t ws_size,
                              hipStream_t stream) {
    const float* feat  = (const float*)d_in[0];
    const float* w_obj = (const float*)d_in[1];
    const float* b_obj = (const float*)d_in[2];
    const float* w_cls = (const float*)d_in[3];
    const float* b_cls = (const float*)d_in[4];
    const float* w_reg = (const float*)d_in[5];
    const float* b_reg = (const float*)d_in[6];
    float* out = (float*)d_out;
    float* ws  = (float*)d_ws;

    float* Wpk    = ws + WS_WPK;
    float* boxes  = ws + WS_BOXES;
    float* scores = ws + WS_SCORES;
    int*   labels = (int*)(ws + WS_LABELS);

    k0_pack<<<(Cc + 63) / 64, 64, 0, stream>>>(w_obj, w_cls, w_reg, Wpk);
    k1_fused<<<NBLK, 256, 0, stream>>>(feat, Wpk, b_obj, b_cls, b_reg,
                                       out, boxes, scores, labels);
    k3_nms<<<Bn * NCx, 256, 0, stream>>>((const float4*)boxes, scores, labels, out);
}